// Round 10
// baseline (11920.152 us; speedup 1.0000x reference)
//
#include <hip/hip_runtime.h>
#include <stdint.h>

#define V_N 100000
#define E_N 50000
#define C_N 128

typedef unsigned short u16;
typedef unsigned int u32;

// ---------- bf16 helpers ----------
__device__ __forceinline__ float bf2f(u16 x) {
    union { u32 i; float f; } c; c.i = ((u32)x) << 16; return c.f;
}
__device__ __forceinline__ u16 f2bf(float f) {
    union { float f; u32 i; } c; c.f = f;
    u32 i = c.i;
    i += 0x7fffu + ((i >> 16) & 1u);   // RNE
    return (u16)(i >> 16);
}
__device__ __forceinline__ void unpack2(u32 u, float& lo, float& hi) {
    union { u32 i; float f; } a, b;
    a.i = u << 16; b.i = u & 0xffff0000u;
    lo = a.f; hi = b.f;
}

// ---------- utility ----------
__global__ __launch_bounds__(256) void zero_f4(float4* __restrict__ p, int n) {
    int i = blockIdx.x * 256 + threadIdx.x;
    if (i < n) { float4 z = {0.f, 0.f, 0.f, 0.f}; p[i] = z; }
}

__global__ __launch_bounds__(64) void flagf_k(float* out, float v) {
    if (threadIdx.x == 0 && blockIdx.x == 0) out[0] = v;
}

__global__ __launch_bounds__(256) void counts_k(const int* __restrict__ v_ids,
                                                const int* __restrict__ e_ids,
                                                float* __restrict__ cnt_e,
                                                float* __restrict__ cnt_v, int nnz) {
    int i = blockIdx.x * 256 + threadIdx.x;
    if (i < nnz) {
        int e = e_ids[i], v = v_ids[i];
        if ((unsigned)e < (unsigned)E_N) unsafeAtomicAdd(cnt_e + e, 1.0f);
        if ((unsigned)v < (unsigned)V_N) unsafeAtomicAdd(cnt_v + v, 1.0f);
    }
}

// ---------- GEMM1 (as-shown jax binding): Xp[m][n] = bf16( sum_k X[m][k]*W[k][n] + b[n] ) ----------
__global__ __launch_bounds__(256) void gemm1_simple(const float* __restrict__ A,
                                                    const float* __restrict__ W,
                                                    const float* __restrict__ bias,
                                                    u16* __restrict__ Cout, int M) {
    int gid = blockIdx.x * 256 + threadIdx.x;
    if (gid >= M * C_N) return;
    int m = gid >> 7;
    int n = gid & 127;
    const float* a = A + (size_t)m * C_N;
    float acc = 0.f;
    #pragma unroll 8
    for (int k = 0; k < C_N; ++k)
        acc += a[k] * W[k * C_N + n];
    Cout[gid] = f2bf(acc + bias[n]);
}

// ---------- GEMM2: Yp[m][n] = bf16( (sum_k relu(Ysum[m][k])*W[k][n]) * inv + b[n] ) ----------
// relu(x)/c == relu(x/c) for c>0; 1/cnt factors out of the K-sum. cnt==0 rows: Ysum==0 -> b only. ✓
__global__ __launch_bounds__(256) void gemm2_simple(const float* __restrict__ Ysum,
                                                    const float* __restrict__ cnt,
                                                    const float* __restrict__ W,
                                                    const float* __restrict__ bias,
                                                    u16* __restrict__ Cout, int M) {
    int gid = blockIdx.x * 256 + threadIdx.x;
    if (gid >= M * C_N) return;
    int m = gid >> 7;
    int n = gid & 127;
    const float* a = Ysum + (size_t)m * C_N;
    float acc = 0.f;
    #pragma unroll 8
    for (int k = 0; k < C_N; ++k)
        acc += fmaxf(a[k], 0.f) * W[k * C_N + n];
    float inv = 1.0f / fmaxf(cnt[m], 1.0f);
    Cout[gid] = f2bf(acc * inv + bias[n]);
}

// ---------- scatter: Accum[dst[i]][c] += Feat[src[i]][c]  (bf16 feats, f32 accum) ----------
__global__ __launch_bounds__(256) void scatter_k(const u16* __restrict__ Feat,
                                                 const int* __restrict__ src_ids,
                                                 const int* __restrict__ dst_ids,
                                                 float* __restrict__ Accum,
                                                 int nnz, int srcN, int dstN) {
    int gid = blockIdx.x * 256 + threadIdx.x;
    int entry = gid >> 4;
    if (entry >= nnz) return;
    int part = gid & 15;
    int s = src_ids[entry];
    int d = dst_ids[entry];
    if ((unsigned)s >= (unsigned)srcN || (unsigned)d >= (unsigned)dstN) return;
    union { uint4 v; u32 u[4]; } q;
    q.v = *(const uint4*)(Feat + (size_t)s * 128 + part * 8);
    float* o = Accum + (size_t)d * 128 + part * 8;
    #pragma unroll
    for (int h = 0; h < 4; ++h) {
        float lo, hi;
        unpack2(q.u[h], lo, hi);
        unsafeAtomicAdd(o + 2 * h + 0, lo);
        unsafeAtomicAdd(o + 2 * h + 1, hi);
    }
}

// ---------- finalize IN PLACE on f32 out: out[v][c] = relu(out[v][c]) / max(cnt_v[v],1) ----------
__global__ __launch_bounds__(256) void finalize_k(float* __restrict__ out,
                                                  const float* __restrict__ cnt_v, int V) {
    int gid = blockIdx.x * 256 + threadIdx.x;
    int v = gid >> 4;
    if (v >= V) return;
    int part = gid & 15;
    float inv = 1.0f / fmaxf(cnt_v[v], 1.0f);
    float4* p = (float4*)(out + (size_t)v * 128 + part * 8);
    float4 x0 = p[0], x1 = p[1];
    x0.x = fmaxf(x0.x * inv, 0.f);
    x0.y = fmaxf(x0.y * inv, 0.f);
    x0.z = fmaxf(x0.z * inv, 0.f);
    x0.w = fmaxf(x0.w * inv, 0.f);
    x1.x = fmaxf(x1.x * inv, 0.f);
    x1.y = fmaxf(x1.y * inv, 0.f);
    x1.z = fmaxf(x1.z * inv, 0.f);
    x1.w = fmaxf(x1.w * inv, 0.f);
    p[0] = x0; p[1] = x1;
}

// ---------- launch ----------
extern "C" void kernel_launch(void* const* d_in, const int* in_sizes, int n_in,
                              void* d_out, int out_size, void* d_ws, size_t ws_size,
                              hipStream_t stream) {
    const float* X     = (const float*)d_in[0];
    const float* W_v2e = (const float*)d_in[1];
    const float* b_v2e = (const float*)d_in[2];
    const float* W_e2v = (const float*)d_in[3];
    const float* b_e2v = (const float*)d_in[4];
    const int*   v_ids = (const int*)d_in[5];
    const int*   e_ids = (const int*)d_in[6];
    float* out = (float*)d_out;                  // f32 output (decoded as f32, compared in bf16 domain)

    bool sizesOK = (n_in == 7) && (out_size == 12800000)
        && in_sizes[0] == 12800000 && in_sizes[1] == 16384 && in_sizes[2] == 128
        && in_sizes[3] == 16384 && in_sizes[4] == 128
        && in_sizes[5] == 1600000 && in_sizes[6] == 1600000;
    if (!sizesOK) { flagf_k<<<1, 64, 0, stream>>>(out, 1.0e6f); return; }
    if (ws_size < 64600000) { flagf_k<<<1, 64, 0, stream>>>(out, 2.0e6f); return; }
    const int nnz = in_sizes[5];

    // workspace layout (bytes):
    //   [0,      25.6M)  Xp   bf16 [V][128]
    //   [25.6M,  51.2M)  Ysum f32  [E][128]
    //   [51.2M,  64.0M)  Yp   bf16 [E][128]
    //   [64.0M,  64.2M)  cnt_e f32 [E]
    //   [64.2M,  64.6M)  cnt_v f32 [V]
    // Xo accumulates directly in d_out (f32, zeroed below).
    char* ws = (char*)d_ws;
    u16*   Xp    = (u16*)  (ws + 0);
    float* Ysum  = (float*)(ws + 25600000);
    u16*   Yp    = (u16*)  (ws + 51200000);
    float* cnt_e = (float*)(ws + 64000000);
    float* cnt_v = (float*)(ws + 64200000);

    // zero output accumulator + Ysum + counts (all re-poisoned by harness each call)
    zero_f4<<<(V_N * C_N / 4 + 255) / 256, 256, 0, stream>>>((float4*)out, V_N * C_N / 4);
    zero_f4<<<(E_N * C_N / 4 + 255) / 256, 256, 0, stream>>>((float4*)Ysum, E_N * C_N / 4);
    zero_f4<<<((E_N + V_N) / 4 + 255) / 256, 256, 0, stream>>>((float4*)cnt_e, (E_N + V_N) / 4);
    counts_k<<<(nnz + 255) / 256, 256, 0, stream>>>(v_ids, e_ids, cnt_e, cnt_v, nnz);

    gemm1_simple<<<(V_N * C_N + 255) / 256, 256, 0, stream>>>(X, W_v2e, b_v2e, Xp, V_N);
    scatter_k<<<((size_t)nnz * 16 + 255) / 256, 256, 0, stream>>>(Xp, v_ids, e_ids, Ysum, nnz, V_N, E_N);
    gemm2_simple<<<(E_N * C_N + 255) / 256, 256, 0, stream>>>(Ysum, cnt_e, W_e2v, b_e2v, Yp, E_N);

    scatter_k<<<((size_t)nnz * 16 + 255) / 256, 256, 0, stream>>>(Yp, e_ids, v_ids, out, nnz, E_N, V_N);
    finalize_k<<<(V_N * 16 + 255) / 256, 256, 0, stream>>>(out, cnt_v, V_N);

    (void)ws_size;
}

// Round 11
// 1442.805 us; speedup vs baseline: 8.2618x; 8.2618x over previous
//
#include <hip/hip_runtime.h>
#include <stdint.h>

#define V_N 100000
#define E_N 50000
#define C_N 128

typedef unsigned short u16;
typedef unsigned int u32;

// ---------- bf16 helpers ----------
__device__ __forceinline__ u16 f2bf(float f) {
    union { float f; u32 i; } c; c.f = f;
    u32 i = c.i;
    i += 0x7fffu + ((i >> 16) & 1u);   // RNE
    return (u16)(i >> 16);
}
__device__ __forceinline__ void unpack2(u32 u, float& lo, float& hi) {
    union { u32 i; float f; } a, b;
    a.i = u << 16; b.i = u & 0xffff0000u;
    lo = a.f; hi = b.f;
}

__global__ __launch_bounds__(64) void flagf_k(float* out, float v) {
    if (threadIdx.x == 0 && blockIdx.x == 0) out[0] = v;
}

__global__ __launch_bounds__(256) void zero_i4(int4* __restrict__ p, int n) {
    int i = blockIdx.x * 256 + threadIdx.x;
    if (i < n) { int4 z = {0, 0, 0, 0}; p[i] = z; }
}

// ---------- histogram (int) ----------
__global__ __launch_bounds__(256) void hist_k(const int* __restrict__ v_ids,
                                              const int* __restrict__ e_ids,
                                              int* __restrict__ icnt_e,
                                              int* __restrict__ icnt_v, int nnz) {
    int i = blockIdx.x * 256 + threadIdx.x;
    if (i < nnz) {
        int e = e_ids[i], v = v_ids[i];
        if ((unsigned)e < (unsigned)E_N && (unsigned)v < (unsigned)V_N) {
            atomicAdd(icnt_e + e, 1);
            atomicAdd(icnt_v + v, 1);
        }
    }
}

// ---------- exclusive scan (2 blocks: block 0 -> edges, block 1 -> verts) ----------
__global__ __launch_bounds__(1024) void scan2_k(const int* __restrict__ icnt_e,
                                                int* __restrict__ off_e, int* __restrict__ cur_e,
                                                const int* __restrict__ icnt_v,
                                                int* __restrict__ off_v, int* __restrict__ cur_v) {
    __shared__ int s[1024];
    __shared__ int carry_s;
    const int* cnt; int* off; int* cur; int n;
    if (blockIdx.x == 0) { cnt = icnt_e; off = off_e; cur = cur_e; n = E_N; }
    else                 { cnt = icnt_v; off = off_v; cur = cur_v; n = V_N; }
    const int tid = threadIdx.x;
    if (tid == 0) carry_s = 0;
    __syncthreads();
    for (int base = 0; base < n; base += 1024) {
        int x = (base + tid < n) ? cnt[base + tid] : 0;
        s[tid] = x; __syncthreads();
        #pragma unroll
        for (int d = 1; d < 1024; d <<= 1) {
            int t = (tid >= d) ? s[tid - d] : 0;
            __syncthreads();
            s[tid] += t;
            __syncthreads();
        }
        int incl = s[tid];
        int carry = carry_s;
        int excl = carry + incl - x;
        if (base + tid < n) { off[base + tid] = excl; cur[base + tid] = excl; }
        __syncthreads();
        if (tid == 1023) carry_s = carry + incl;
        __syncthreads();
    }
    if (tid == 0) off[n] = carry_s;
}

// ---------- fill CSR adjacency (order within segment nondeterministic; sums commute) ----------
__global__ __launch_bounds__(256) void fill_k(const int* __restrict__ v_ids,
                                              const int* __restrict__ e_ids,
                                              int* __restrict__ cur_e, int* __restrict__ cur_v,
                                              int* __restrict__ se_src, int* __restrict__ sv_src,
                                              int nnz) {
    int i = blockIdx.x * 256 + threadIdx.x;
    if (i < nnz) {
        int e = e_ids[i], v = v_ids[i];
        if ((unsigned)e < (unsigned)E_N && (unsigned)v < (unsigned)V_N) {
            int pe = atomicAdd(cur_e + e, 1); se_src[pe] = v;
            int pv = atomicAdd(cur_v + v, 1); sv_src[pv] = e;
        }
    }
}

// ---------- GEMM1: Xp[m][n] = bf16( sum_k X[m][k]*W[k][n] + b[n] ) ----------
__global__ __launch_bounds__(256) void gemm1_simple(const float* __restrict__ A,
                                                    const float* __restrict__ W,
                                                    const float* __restrict__ bias,
                                                    u16* __restrict__ Cout, int M) {
    int gid = blockIdx.x * 256 + threadIdx.x;
    if (gid >= M * C_N) return;
    int m = gid >> 7;
    int n = gid & 127;
    const float* a = A + (size_t)m * C_N;
    float acc = 0.f;
    #pragma unroll 8
    for (int k = 0; k < C_N; ++k)
        acc += a[k] * W[k * C_N + n];
    Cout[gid] = f2bf(acc + bias[n]);
}

// ---------- seg_e: Ysum[e][c] = sum over segment of Xp[src][c]  (1 wave per edge) ----------
__global__ __launch_bounds__(256) void seg_e_k(const u16* __restrict__ Xp,
                                               const int* __restrict__ off,
                                               const int* __restrict__ srcs,
                                               float* __restrict__ Ysum, int E) {
    int e = blockIdx.x * 4 + (threadIdx.x >> 6);
    if (e >= E) return;
    int lane = threadIdx.x & 63;
    int j0 = off[e], j1 = off[e + 1];
    float a0 = 0.f, a1 = 0.f;
    int j = j0;
    for (; j + 1 < j1; j += 2) {
        int s0 = srcs[j], s1 = srcs[j + 1];
        u32 q0 = ((const u32*)(Xp + (size_t)s0 * C_N))[lane];
        u32 q1 = ((const u32*)(Xp + (size_t)s1 * C_N))[lane];
        float l0, h0, l1, h1;
        unpack2(q0, l0, h0); unpack2(q1, l1, h1);
        a0 += l0 + l1; a1 += h0 + h1;
    }
    if (j < j1) {
        int s0 = srcs[j];
        u32 q0 = ((const u32*)(Xp + (size_t)s0 * C_N))[lane];
        float l0, h0; unpack2(q0, l0, h0);
        a0 += l0; a1 += h0;
    }
    float2 w; w.x = a0; w.y = a1;
    ((float2*)Ysum)[(size_t)e * 64 + lane] = w;
}

// ---------- GEMM2: Yp[m][n] = bf16( (sum_k relu(Ysum[m][k])*W[k][n]) / max(len,1) + b[n] ) ----------
__global__ __launch_bounds__(256) void gemm2_simple(const float* __restrict__ Ysum,
                                                    const int* __restrict__ off,
                                                    const float* __restrict__ W,
                                                    const float* __restrict__ bias,
                                                    u16* __restrict__ Cout, int M) {
    int gid = blockIdx.x * 256 + threadIdx.x;
    if (gid >= M * C_N) return;
    int m = gid >> 7;
    int n = gid & 127;
    const float* a = Ysum + (size_t)m * C_N;
    float acc = 0.f;
    #pragma unroll 8
    for (int k = 0; k < C_N; ++k)
        acc += fmaxf(a[k], 0.f) * W[k * C_N + n];
    int len = off[m + 1] - off[m];
    float inv = 1.0f / (float)max(len, 1);
    Cout[gid] = f2bf(acc * inv + bias[n]);
}

// ---------- seg_v: out[v][c] = relu( sum Yp[src][c] / max(len,1) )  (1 wave per vertex) ----------
__global__ __launch_bounds__(256) void seg_v_k(const u16* __restrict__ Yp,
                                               const int* __restrict__ off,
                                               const int* __restrict__ srcs,
                                               float* __restrict__ out, int V) {
    int v = blockIdx.x * 4 + (threadIdx.x >> 6);
    if (v >= V) return;
    int lane = threadIdx.x & 63;
    int j0 = off[v], j1 = off[v + 1];
    float a0 = 0.f, a1 = 0.f;
    int j = j0;
    for (; j + 1 < j1; j += 2) {
        int s0 = srcs[j], s1 = srcs[j + 1];
        u32 q0 = ((const u32*)(Yp + (size_t)s0 * C_N))[lane];
        u32 q1 = ((const u32*)(Yp + (size_t)s1 * C_N))[lane];
        float l0, h0, l1, h1;
        unpack2(q0, l0, h0); unpack2(q1, l1, h1);
        a0 += l0 + l1; a1 += h0 + h1;
    }
    if (j < j1) {
        int s0 = srcs[j];
        u32 q0 = ((const u32*)(Yp + (size_t)s0 * C_N))[lane];
        float l0, h0; unpack2(q0, l0, h0);
        a0 += l0; a1 += h0;
    }
    float inv = 1.0f / (float)max(j1 - j0, 1);
    float2 w;
    w.x = fmaxf(a0 * inv, 0.f);
    w.y = fmaxf(a1 * inv, 0.f);
    ((float2*)out)[(size_t)v * 64 + lane] = w;
}

// ---------- launch ----------
extern "C" void kernel_launch(void* const* d_in, const int* in_sizes, int n_in,
                              void* d_out, int out_size, void* d_ws, size_t ws_size,
                              hipStream_t stream) {
    const float* X     = (const float*)d_in[0];
    const float* W_v2e = (const float*)d_in[1];
    const float* b_v2e = (const float*)d_in[2];
    const float* W_e2v = (const float*)d_in[3];
    const float* b_e2v = (const float*)d_in[4];
    const int*   v_ids = (const int*)d_in[5];
    const int*   e_ids = (const int*)d_in[6];
    float* out = (float*)d_out;   // f32 [V][128]

    bool sizesOK = (n_in == 7) && (out_size == 12800000)
        && in_sizes[0] == 12800000 && in_sizes[1] == 16384 && in_sizes[2] == 128
        && in_sizes[3] == 16384 && in_sizes[4] == 128
        && in_sizes[5] == 1600000 && in_sizes[6] == 1600000;
    if (!sizesOK) { flagf_k<<<1, 64, 0, stream>>>(out, 1.0e6f); return; }
    if (ws_size < 28000000) { flagf_k<<<1, 64, 0, stream>>>(out, 2.0e6f); return; }
    const int nnz = in_sizes[5];

    // d_out doubles as scratch for the first half (both regions dead before seg_v):
    //   d_out[0,        25.6M)  Xp   bf16 [V][128]
    //   d_out[25.6M,    51.2M)  Ysum f32  [E][128]
    u16*   Xp   = (u16*)d_out;
    float* Ysum = (float*)((char*)d_out + 25600000);

    // ws layout (bytes), all int/bf16 scratch:
    //   [0,       12.8M)  Yp bf16 [E][128]
    //   [12.8M,   19.2M)  se_src int[nnz]
    //   [19.2M,   25.6M)  sv_src int[nnz]
    //   [25.6M,  +200K )  icnt_e[50000]
    //   ...               icnt_v[100000], off_e[50001+pad], off_v[100001+pad], cur_e, cur_v
    char* ws = (char*)d_ws;
    u16* Yp     = (u16*)(ws + 0);
    int* se_src = (int*)(ws + 12800000);
    int* sv_src = (int*)(ws + 19200000);
    int* icnt_e = (int*)(ws + 25600000);            // 50000
    int* icnt_v = (int*)(ws + 25800000);            // 100000
    int* off_e  = (int*)(ws + 26200000);            // 50001 (+pad to 50016)
    int* off_v  = (int*)(ws + 26400064);            // 100001 (+pad)
    int* cur_e  = (int*)(ws + 26800128);            // 50000
    int* cur_v  = (int*)(ws + 27000128);            // 100000

    // zero histograms (icnt_e..icnt_v contiguous: 150000 ints)
    zero_i4<<<(150000 / 4 + 255) / 256, 256, 0, stream>>>((int4*)icnt_e, 150000 / 4);
    hist_k<<<(nnz + 255) / 256, 256, 0, stream>>>(v_ids, e_ids, icnt_e, icnt_v, nnz);
    scan2_k<<<2, 1024, 0, stream>>>(icnt_e, off_e, cur_e, icnt_v, off_v, cur_v);
    fill_k<<<(nnz + 255) / 256, 256, 0, stream>>>(v_ids, e_ids, cur_e, cur_v, se_src, sv_src, nnz);

    gemm1_simple<<<(V_N * C_N + 255) / 256, 256, 0, stream>>>(X, W_v2e, b_v2e, Xp, V_N);
    seg_e_k<<<(E_N + 3) / 4, 256, 0, stream>>>(Xp, off_e, se_src, Ysum, E_N);
    gemm2_simple<<<(E_N * C_N + 255) / 256, 256, 0, stream>>>(Ysum, off_e, W_e2v, b_e2v, Yp, E_N);
    seg_v_k<<<(V_N + 3) / 4, 256, 0, stream>>>(Yp, off_v, sv_src, out, V_N);

    (void)ws_size;
}